// Round 10
// baseline (335.788 us; speedup 1.0000x reference)
//
#include <hip/hip_runtime.h>

// GIN regressor: 3x [segment-sum aggregation -> (1+eps)*x+agg -> Linear/ReLU/Linear]
// -> global mean pool -> fc.
// CSR via LDS-binned coarse-bucket counting sort (write-amp fixed r7-r9).
// Feature tables stored FEATURE-SLICED: [8 slices][N][16 feats] bf16. Aggregation
// pins slice s to XCD s (blockIdx&7; HW round-robins blocks over XCDs) so each
// XCD's gathers hit its 1.6MB L2-resident slice instead of missing a 12.8MB table.
// GEMMs = bf16 MFMA (fp32 accum, pre-swizzled W), A-loads/stores in sliced layout.
// Layer-2: second GEMM folded into pool (weff = W2@fcw); its first GEMM's
// epilogue computes pooled per-graph sums directly.

#define FEAT 128
#define BCAP 2048          // per-bucket capacity (mean load ~1024)
#define CHUNK 10240        // edges per bucket-kernel block

typedef short  bf16x8 __attribute__((ext_vector_type(8)));
typedef float  f32x4  __attribute__((ext_vector_type(4)));

__device__ inline unsigned short f2bf(float f) {  // round-to-nearest-even fp32->bf16
    unsigned int u = __float_as_uint(f);
    u = (u + 0x7FFFu + ((u >> 16) & 1u)) >> 16;
    return (unsigned short)u;
}
__device__ inline float2 bfpair(unsigned int u) { // packed 2x bf16 -> 2x fp32
    float2 r;
    r.x = __uint_as_float(u << 16);
    r.y = __uint_as_float(u & 0xffff0000u);
    return r;
}

// ---------------- CSR build: LDS-binned coarse-bucket counting sort ----------
__global__ __launch_bounds__(1024) void bucket_kernel(
    const int* __restrict__ src, const int* __restrict__ dst,
    int* __restrict__ bcnt, unsigned int* __restrict__ bpairs, int E) {
    __shared__ unsigned int lpairs[CHUNK];   // 40KB: bucket-ordered pairs
    __shared__ int lbase[1025];
    __shared__ int lcur[1024];
    __shared__ int lres[1024];
    __shared__ int part[1024];
    int tid = threadIdx.x;
    int e0 = blockIdx.x * CHUNK;
    int e1 = e0 + CHUNK; if (e1 > E) e1 = E;
    int cnt = e1 - e0;
    lcur[tid] = 0;
    __syncthreads();
    for (int e = e0 + tid; e < e1; e += 1024) atomicAdd(&lcur[dst[e] >> 6], 1);
    __syncthreads();
    int v = lcur[tid];
    part[tid] = v;
    __syncthreads();
    for (int d = 1; d < 1024; d <<= 1) {
        int u = (tid >= d) ? part[tid - d] : 0;
        __syncthreads();
        part[tid] += u;
        __syncthreads();
    }
    int ex = part[tid] - v;
    lbase[tid] = ex;
    if (tid == 1023) lbase[1024] = part[1023];
    lcur[tid] = ex;
    lres[tid] = (v > 0) ? atomicAdd(&bcnt[tid * 16], v) : 0;
    __syncthreads();
    for (int e = e0 + tid; e < e1; e += 1024) {
        int d = dst[e], s = src[e];
        int p = atomicAdd(&lcur[d >> 6], 1);
        lpairs[p] = ((unsigned int)s << 6) | (unsigned int)(d & 63);
    }
    __syncthreads();
    for (int j = tid; j < cnt; j += 1024) {
        int lo = 0, hi = 1023;
        while (lo < hi) { int m = (lo + hi + 1) >> 1; if (lbase[m] <= j) lo = m; else hi = m - 1; }
        int gpos = lres[lo] + (j - lbase[lo]);
        if (gpos < BCAP) bpairs[(size_t)lo * BCAP + gpos] = lpairs[j];
    }
}

// Phase 2: per-bucket LDS histogram -> node degrees.
__global__ __launch_bounds__(256) void deg_kernel(const int* __restrict__ bcnt,
                                                  const unsigned int* __restrict__ bpairs,
                                                  int* __restrict__ off, int n) {
    __shared__ int lh[64];
    int b = blockIdx.x, tid = threadIdx.x;
    if (tid < 64) lh[tid] = 0;
    __syncthreads();
    int cnt = bcnt[b * 16]; if (cnt > BCAP) cnt = BCAP;
    const unsigned int* bp = bpairs + (size_t)b * BCAP;
    for (int i = tid; i < cnt; i += 256) atomicAdd(&lh[bp[i] & 63u], 1);
    __syncthreads();
    if (tid < 64) {
        int node = b * 64 + tid;
        if (node < n) off[node] = lh[tid];
    }
}

// Phase A: blocksums[b] = sum(off[b*1024 .. +1023])
__global__ void block_sum_kernel(const int* __restrict__ off, int* __restrict__ bs, int n) {
    int b = blockIdx.x, t = threadIdx.x;   // 256 threads
    int base = b * 1024;
    int s = 0;
    #pragma unroll
    for (int i = 0; i < 4; ++i) {
        int idx = base + t + 256 * i;
        if (idx < n) s += off[idx];
    }
    #pragma unroll
    for (int d = 32; d; d >>= 1) s += __shfl_down(s, d, 64);
    __shared__ int ws[4];
    if ((t & 63) == 0) ws[t >> 6] = s;
    __syncthreads();
    if (t == 0) bs[b] = ws[0] + ws[1] + ws[2] + ws[3];
}

__global__ void scan_blocksums_kernel(int* __restrict__ bs, int nb,
                                      int* __restrict__ off, int n) {
    __shared__ int l[1024];
    int t = threadIdx.x;
    int v = (t < nb) ? bs[t] : 0;
    l[t] = v;
    __syncthreads();
    for (int d = 1; d < 1024; d <<= 1) {
        int u = (t >= d) ? l[t - d] : 0;
        __syncthreads();
        l[t] += u;
        __syncthreads();
    }
    if (t < nb) bs[t] = (t == 0) ? 0 : l[t - 1];
    if (t == 1023) off[n] = l[1023];
}

__global__ __launch_bounds__(256) void block_scan_kernel(
    int* __restrict__ off, const int* __restrict__ bs, int n) {
    __shared__ int l[1024];
    __shared__ int part[256];
    int b = blockIdx.x, t = threadIdx.x;
    int base = b * 1024;
    #pragma unroll
    for (int i = 0; i < 4; ++i) {
        int idx = base + t + 256 * i;
        l[t + 256 * i] = (idx < n) ? off[idx] : 0;
    }
    __syncthreads();
    int v0 = l[4 * t], v1 = l[4 * t + 1], v2 = l[4 * t + 2], v3 = l[4 * t + 3];
    int p = v0 + v1 + v2 + v3;
    part[t] = p;
    __syncthreads();
    for (int d = 1; d < 256; d <<= 1) {
        int u = (t >= d) ? part[t - d] : 0;
        __syncthreads();
        part[t] += u;
        __syncthreads();
    }
    int ex = bs[b] + ((t == 0) ? 0 : part[t - 1]);
    int e0 = ex, e1 = ex + v0, e2 = e1 + v1, e3 = e2 + v2;
    int idx = base + 4 * t;
    if (idx + 3 < n) {
        ((int4*)(off + idx))[0] = make_int4(e0, e1, e2, e3);
    } else {
        if (idx + 0 < n) off[idx + 0] = e0;
        if (idx + 1 < n) off[idx + 1] = e1;
        if (idx + 2 < n) off[idx + 2] = e2;
    }
}

// Phase 3: per-bucket scatter with LDS cursors.
__global__ __launch_bounds__(256) void bucket_scatter_kernel(
    const int* __restrict__ bcnt, const unsigned int* __restrict__ bpairs,
    const int* __restrict__ off, int* __restrict__ srcs, int n) {
    __shared__ int lcur[64];
    int b = blockIdx.x, tid = threadIdx.x;
    if (tid < 64) {
        int node = b * 64 + tid;
        lcur[tid] = (node < n) ? off[node] : 0;
    }
    __syncthreads();
    int cnt = bcnt[b * 16]; if (cnt > BCAP) cnt = BCAP;
    const unsigned int* bp = bpairs + (size_t)b * BCAP;
    for (int i = tid; i < cnt; i += 256) {
        unsigned int pr = bp[i];
        int pos = atomicAdd(&lcur[pr & 63u], 1);
        srcs[pos] = (int)(pr >> 6);
    }
}

// ---------------- fused setup: xbf(sliced) | gstart | weff | wprep -----------
__global__ __launch_bounds__(256) void setup_kernel(
    const float* __restrict__ x, unsigned int* __restrict__ xbf, long pairs, int nxb,
    const int* __restrict__ batch, int* __restrict__ gstart, int n, int G,
    const float* __restrict__ W2f, const float* __restrict__ b2f,
    const float* __restrict__ fcw, float* __restrict__ weff,
    const float* __restrict__ W0, const float* __restrict__ W1,
    const float* __restrict__ W2, const float* __restrict__ W3,
    const float* __restrict__ W4, unsigned short* __restrict__ Wswz) {
    int b = blockIdx.x, tid = threadIdx.x;
    if (b < nxb) {                       // cast x -> SLICED packed bf16
        long i = (long)b * 256 + tid;    // i = node*64 + dglob
        if (i < pairs) {
            float2 v = ((const float2*)x)[i];
            unsigned int pk = (unsigned int)f2bf(v.x) | ((unsigned int)f2bf(v.y) << 16);
            long node = i >> 6;
            int dg = (int)(i & 63);
            int slice = dg >> 3, d = dg & 7;
            xbf[(size_t)slice * n * 8 + node * 8 + d] = pk;
        }
    } else if (b < nxb + 2) {            // gstart[g] = lower_bound(batch, g)
        int i = (b - nxb) * 256 + tid;
        if (i <= G) {
            int lo = 0, hi = n;
            while (lo < hi) { int m = (lo + hi) >> 1; if (batch[m] < i) lo = m + 1; else hi = m; }
            gstart[i] = lo;
        }
    } else if (b == nxb + 2) {           // weff = W2@fcw ; weff[128] = b2.fcw
        int lane = tid & 63, wave = tid >> 6;
        float2 f2 = ((const float2*)fcw)[lane];
        for (int r = wave; r < 128; r += 4) {
            float2 w = ((const float2*)(W2f + r * FEAT))[lane];
            float d = w.x * f2.x + w.y * f2.y;
            #pragma unroll
            for (int s = 32; s; s >>= 1) d += __shfl_down(d, s, 64);
            if (lane == 0) weff[r] = d;
        }
        if (wave == 0) {
            float2 bb = ((const float2*)b2f)[lane];
            float d = bb.x * f2.x + bb.y * f2.y;
            #pragma unroll
            for (int s = 32; s; s >>= 1) d += __shfl_down(d, s, 64);
            if (lane == 0) weff[128] = d;
        }
    } else {                             // wprep: swizzled bf16 weights
        int gid = (b - nxb - 3) * 256 + tid;
        if (gid < 5 * 2048) {
            int mat = gid >> 11;
            int task = gid & 2047;
            int c = task >> 4, m = task & 15;
            const float* W = (mat == 0) ? W0 : (mat == 1) ? W1 : (mat == 2) ? W2 :
                             (mat == 3) ? W3 : W4;
            unsigned short* dp = Wswz + mat * 16384 + c * 128 + ((m ^ (c & 7)) << 3);
            #pragma unroll
            for (int j = 0; j < 8; ++j) dp[j] = f2bf(W[(8 * m + j) * FEAT + c]);
        }
    }
}

// ---------------- aggregation + (1+eps)*h -> sliced bf16 pre -----------------
// Sliced tables [8][n][8 dwords]. Block handles 32 nodes x 1 slice; slice =
// blockIdx&7 pins each slice to one XCD (1.6MB slice stays L2-resident).
// Wave = 8 node-groups x 8 lanes; each group's gather = 32B contiguous.
__global__ __launch_bounds__(256) void agg_kernel(
    const unsigned int* __restrict__ hs, const int* __restrict__ off,
    const int* __restrict__ srcs, const float* __restrict__ eps_p,
    unsigned int* __restrict__ pre, int n) {
    int b = blockIdx.x;
    int slice = b & 7;
    int chunk = b >> 3;
    int tid = threadIdx.x;
    int wave = tid >> 6, lane = tid & 63;
    int g = lane >> 3, d = lane & 7;
    int node = chunk * 32 + wave * 8 + g;
    if (node >= n) return;
    float eps1 = 1.0f + eps_p[0];
    const unsigned int* hb = hs + (size_t)slice * n * 8;
    float2 self = bfpair(hb[(size_t)node * 8 + d]);
    float2 acc0 = make_float2(self.x * eps1, self.y * eps1);
    float2 acc1 = make_float2(0.f, 0.f);
    float2 acc2 = make_float2(0.f, 0.f);
    float2 acc3 = make_float2(0.f, 0.f);
    int j0 = off[node], j1 = off[node + 1];
    int j = j0;
    for (; j + 4 <= j1; j += 4) {
        int s0 = srcs[j], s1 = srcs[j + 1], s2 = srcs[j + 2], s3 = srcs[j + 3];
        unsigned int u0 = hb[(size_t)s0 * 8 + d];
        unsigned int u1 = hb[(size_t)s1 * 8 + d];
        unsigned int u2 = hb[(size_t)s2 * 8 + d];
        unsigned int u3 = hb[(size_t)s3 * 8 + d];
        float2 v0 = bfpair(u0), v1 = bfpair(u1), v2 = bfpair(u2), v3 = bfpair(u3);
        acc0.x += v0.x; acc0.y += v0.y;  acc1.x += v1.x; acc1.y += v1.y;
        acc2.x += v2.x; acc2.y += v2.y;  acc3.x += v3.x; acc3.y += v3.y;
    }
    for (; j < j1; ++j) {
        int s = srcs[j];
        float2 v = bfpair(hb[(size_t)s * 8 + d]);
        acc0.x += v.x; acc0.y += v.y;
    }
    acc0.x += acc1.x + acc2.x;
    acc0.y += acc1.y + acc2.y;
    acc0.x += acc3.x;
    acc0.y += acc3.y;
    pre[(size_t)slice * n * 8 + (size_t)node * 8 + d] =
        (unsigned int)f2bf(acc0.x) | ((unsigned int)f2bf(acc0.y) << 16);
}

// ---------------- bf16 MFMA GEMM over SLICED A. MODE 1: sliced store. MODE 2: pool ----
// A sliced [8][n][16] bf16: feats 32k0+8q..+7 live at slice 2k0+(q>>1), elem 8(q&1).
template <int MODE>
__global__ __launch_bounds__(256) void mfma_mlp_kernel(
    const unsigned short* __restrict__ A, const unsigned short* __restrict__ Wswz,
    const float* __restrict__ bias, unsigned short* __restrict__ outbf,
    const int* __restrict__ batch, const float* __restrict__ weff,
    float* __restrict__ sums, int n) {
    __shared__ int4 Wl4[2048];   // 32KB swizzled W
    int tid = threadIdx.x;
    const int4* ws4 = (const int4*)Wswz;
    #pragma unroll
    for (int i = 0; i < 8; ++i) Wl4[i * 256 + tid] = ws4[i * 256 + tid];
    __syncthreads();
    const unsigned short* Wl = (const unsigned short*)Wl4;

    int lane = tid & 63, wave = tid >> 6;
    int q = lane >> 4, c15 = lane & 15;
    int r0 = blockIdx.x * 64 + wave * 16;
    int arow = r0 + c15;
    bool rv = arow < n;
    size_t sstride = (size_t)n * 16;
    const unsigned short* abase = A + (size_t)arow * 16 + 8 * (q & 1) + (q >> 1) * sstride;

    f32x4 zf = {0.f, 0.f, 0.f, 0.f};
    f32x4 acc[8];
    #pragma unroll
    for (int i = 0; i < 8; ++i) acc[i] = zf;
    bf16x8 zero8 = {0, 0, 0, 0, 0, 0, 0, 0};

    #pragma unroll
    for (int k0 = 0; k0 < 4; ++k0) {
        bf16x8 a = rv ? *(const bf16x8*)(abase + 2 * k0 * sstride) : zero8;
        int m = k0 * 4 + q;
        #pragma unroll
        for (int nt = 0; nt < 8; ++nt) {
            int col = nt * 16 + c15;
            bf16x8 bfr = *(const bf16x8*)&Wl[col * 128 + ((m ^ (col & 7)) << 3)];
            acc[nt] = __builtin_amdgcn_mfma_f32_16x16x32_bf16(a, bfr, acc[nt], 0, 0, 0);
        }
    }

    int orow0 = r0 + q * 4;
    if (MODE == 1) {
        #pragma unroll
        for (int nt = 0; nt < 8; ++nt) {
            float bv = bias[nt * 16 + c15];
            #pragma unroll
            for (int r = 0; r < 4; ++r) {
                int ro = orow0 + r;
                if (ro < n) {
                    float v = fmaxf(acc[nt][r] + bv, 0.f);
                    outbf[(size_t)nt * sstride + (size_t)ro * 16 + c15] = f2bf(v);
                }
            }
        }
    } else {
        // fused pool: rowdot = relu(row)·weff ; per-graph LDS accumulation.
        __shared__ float gsum[64];
        int r0b = blockIdx.x * 64;
        int lastn = r0b + 63 < n - 1 ? r0b + 63 : n - 1;
        int gmin = batch[r0b];
        int gmax = batch[lastn];
        int span = gmax - gmin + 1;
        bool lds_ok = (span <= 64);
        if (lds_ok) for (int i = tid; i < span; i += 256) gsum[i] = 0.f;
        __syncthreads();
        float rowdot[4] = {0.f, 0.f, 0.f, 0.f};
        #pragma unroll
        for (int nt = 0; nt < 8; ++nt) {
            int col = nt * 16 + c15;
            float bv = bias[col];
            float wv = weff[col];
            #pragma unroll
            for (int r = 0; r < 4; ++r)
                rowdot[r] += fmaxf(acc[nt][r] + bv, 0.f) * wv;
        }
        #pragma unroll
        for (int r = 0; r < 4; ++r) {
            float v = rowdot[r];
            v += __shfl_xor(v, 1, 64);
            v += __shfl_xor(v, 2, 64);
            v += __shfl_xor(v, 4, 64);
            v += __shfl_xor(v, 8, 64);
            if (c15 == 0) {
                int node = orow0 + r;
                if (node < n) {
                    int g = batch[node];
                    if (lds_ok) atomicAdd(&gsum[g - gmin], v);
                    else        atomicAdd(&sums[g], v);
                }
            }
        }
        __syncthreads();
        if (lds_ok)
            for (int i = tid; i < span; i += 256) atomicAdd(&sums[gmin + i], gsum[i]);
    }
}

// ---------------- finalize: out[g] = sums/cnt + b2.fcw + fcb ----------------
__global__ void finalize_kernel(const float* __restrict__ sums, const int* __restrict__ gstart,
                                const float* __restrict__ weff, const float* __restrict__ fcb,
                                float* __restrict__ out, int G) {
    int g = blockIdx.x * blockDim.x + threadIdx.x;
    if (g >= G) return;
    int cnt = gstart[g + 1] - gstart[g];
    out[g] = (cnt > 0) ? sums[g] / (float)cnt + weff[128] + fcb[0] : fcb[0];
}

static inline size_t align256(size_t x) { return (x + 255) & ~(size_t)255; }

extern "C" void kernel_launch(void* const* d_in, const int* in_sizes, int n_in,
                              void* d_out, int out_size, void* d_ws, size_t ws_size,
                              hipStream_t stream) {
    const float* x      = (const float*)d_in[0];
    const int*   ei     = (const int*)d_in[1];
    const int*   batch  = (const int*)d_in[2];
    const float* W1[3]  = {(const float*)d_in[3],  (const float*)d_in[8],  (const float*)d_in[13]};
    const float* b1[3]  = {(const float*)d_in[4],  (const float*)d_in[9],  (const float*)d_in[14]};
    const float* W2[3]  = {(const float*)d_in[5],  (const float*)d_in[10], (const float*)d_in[15]};
    const float* b2[3]  = {(const float*)d_in[6],  (const float*)d_in[11], (const float*)d_in[16]};
    const float* eps[3] = {(const float*)d_in[7],  (const float*)d_in[12], (const float*)d_in[17]};
    const float* fcw    = (const float*)d_in[18];
    const float* fcb    = (const float*)d_in[19];
    float* out = (float*)d_out;

    const int N = in_sizes[0] / FEAT;
    const int E = in_sizes[1] / 2;
    const int G = out_size;
    const int nbuckets = (N + 63) >> 6;

    // workspace layout
    char* p = (char*)d_ws;
    int* off    = (int*)p;  p += align256((size_t)(N + 1) * 4);
    int* srcs   = (int*)p;  p += align256((size_t)E * 4);
    int* bsums  = (int*)p;  p += align256((size_t)1024 * 4);
    int* gstart = (int*)p;  p += align256((size_t)(G + 1) * 4);
    float* weff = (float*)p; p += align256((size_t)256 * 4);
    unsigned short* Wswz = (unsigned short*)p; p += align256((size_t)5 * 16384 * 2);
    float* sums = (float*)p;                     // zero-init region start
    char* z0 = (char*)sums;
    p += align256((size_t)G * 4);
    int* bcnt = (int*)p; p += align256((size_t)nbuckets * 16 * 4);
    size_t zbytes = (size_t)(p - z0);            // sums + bcnt in one memset
    unsigned int* bpairs = (unsigned int*)p;     p += align256((size_t)nbuckets * BCAP * 4);
    unsigned int* x_bf   = (unsigned int*)p;     p += align256((size_t)N * 64 * 4);
    unsigned int* pre_bf = (unsigned int*)p;     p += align256((size_t)N * 64 * 4);
    unsigned int* t_bf   = (unsigned int*)p;     p += align256((size_t)N * 64 * 4);
    unsigned int* h_bf   = (unsigned int*)p;     p += align256((size_t)N * 64 * 4);
    (void)ws_size; (void)n_in;

    const int* src = ei;        // edge_index[0]
    const int* dst = ei + E;    // edge_index[1]

    hipMemsetAsync(z0, 0, zbytes, stream);

    // CSR build: LDS-binned bucket (1024 thr) -> deg -> scan -> bucket_scatter
    const int nb = (N + 1023) / 1024;
    const int nchunks = (E + CHUNK - 1) / CHUNK;
    bucket_kernel<<<nchunks, 1024, 0, stream>>>(src, dst, bcnt, bpairs, E);
    deg_kernel<<<nbuckets, 256, 0, stream>>>(bcnt, bpairs, off, N);
    block_sum_kernel<<<nb, 256, 0, stream>>>(off, bsums, N);
    scan_blocksums_kernel<<<1, 1024, 0, stream>>>(bsums, nb, off, N);
    block_scan_kernel<<<nb, 256, 0, stream>>>(off, bsums, N);
    bucket_scatter_kernel<<<nbuckets, 256, 0, stream>>>(bcnt, bpairs, off, srcs, N);

    // fused setup (independent of CSR): xbf(sliced) | gstart | weff | wprep
    long pairs = (long)N * 64;
    int nxb = (int)((pairs + 255) / 256);
    setup_kernel<<<nxb + 43, 256, 0, stream>>>(
        x, x_bf, pairs, nxb, batch, gstart, N, G,
        W2[2], b2[2], fcw, weff,
        W1[0], W2[0], W1[1], W2[1], W1[2], Wswz);

    const int aggBlocks  = 8 * ((N + 31) / 32);   // 8 slices, 32 nodes/block
    const int gemmBlocks = (N + 63) / 64;
    const unsigned short* Wz[5] = {Wswz, Wswz + 16384, Wswz + 2 * 16384,
                                   Wswz + 3 * 16384, Wswz + 4 * 16384};

    // layers 0,1: agg -> gemm1(sliced bf16) -> gemm2(sliced bf16)
    const unsigned int* h = x_bf;
    for (int i = 0; i < 2; ++i) {
        agg_kernel<<<aggBlocks, 256, 0, stream>>>(h, off, srcs, eps[i], pre_bf, N);
        mfma_mlp_kernel<1><<<gemmBlocks, 256, 0, stream>>>(
            (const unsigned short*)pre_bf, Wz[2 * i], b1[i], (unsigned short*)t_bf,
            nullptr, nullptr, nullptr, N);
        mfma_mlp_kernel<1><<<gemmBlocks, 256, 0, stream>>>(
            (const unsigned short*)t_bf, Wz[2 * i + 1], b2[i], (unsigned short*)h_bf,
            nullptr, nullptr, nullptr, N);
        h = h_bf;
    }
    // layer 2: agg -> gemm1 with fused pooled-dot epilogue (W2_2+fc folded via weff)
    agg_kernel<<<aggBlocks, 256, 0, stream>>>(h, off, srcs, eps[2], pre_bf, N);
    mfma_mlp_kernel<2><<<gemmBlocks, 256, 0, stream>>>(
        (const unsigned short*)pre_bf, Wz[4], b1[2], nullptr,
        batch, weff, sums, N);

    finalize_kernel<<<(G + 255) / 256, 256, 0, stream>>>(sums, gstart, weff, fcb, out, G);
}

// Round 11
// 304.690 us; speedup vs baseline: 1.1021x; 1.1021x over previous
//
#include <hip/hip_runtime.h>

// GIN regressor: 3x [segment-sum aggregation -> (1+eps)*x+agg -> Linear/ReLU/Linear]
// -> global mean pool -> fc.
// CSR via LDS-binned coarse-bucket counting sort (write-amp fixed r7-r9).
// Feature tables stored FEATURE-SLICED: [4 slices][N][32 feats] bf16 (3.2MB/slice,
// L2-resident; blockIdx&3 pins slice s to XCDs {s,s+4}). r10 lesson: agg is
// latency/issue-bound, not HBM-bound -> this round gathers 8B/lane (uint2) with
// an 8-deep unroll (8 loads in flight/lane) to halve instructions and double ILP.
// GEMMs = bf16 MFMA (fp32 accum, pre-swizzled W), A-loads/stores sliced.
// Layer-2: second GEMM folded into pool (weff = W2@fcw); its first GEMM's
// epilogue computes pooled per-graph sums directly.

#define FEAT 128
#define BCAP 2048          // per-bucket capacity (mean load ~1024)
#define CHUNK 10240        // edges per bucket-kernel block

typedef short  bf16x8 __attribute__((ext_vector_type(8)));
typedef float  f32x4  __attribute__((ext_vector_type(4)));

__device__ inline unsigned short f2bf(float f) {  // round-to-nearest-even fp32->bf16
    unsigned int u = __float_as_uint(f);
    u = (u + 0x7FFFu + ((u >> 16) & 1u)) >> 16;
    return (unsigned short)u;
}
__device__ inline float2 bfpair(unsigned int u) { // packed 2x bf16 -> 2x fp32
    float2 r;
    r.x = __uint_as_float(u << 16);
    r.y = __uint_as_float(u & 0xffff0000u);
    return r;
}

// ---------------- CSR build: LDS-binned coarse-bucket counting sort ----------
__global__ __launch_bounds__(1024) void bucket_kernel(
    const int* __restrict__ src, const int* __restrict__ dst,
    int* __restrict__ bcnt, unsigned int* __restrict__ bpairs, int E) {
    __shared__ unsigned int lpairs[CHUNK];   // 40KB: bucket-ordered pairs
    __shared__ int lbase[1025];
    __shared__ int lcur[1024];
    __shared__ int lres[1024];
    __shared__ int part[1024];
    int tid = threadIdx.x;
    int e0 = blockIdx.x * CHUNK;
    int e1 = e0 + CHUNK; if (e1 > E) e1 = E;
    int cnt = e1 - e0;
    lcur[tid] = 0;
    __syncthreads();
    for (int e = e0 + tid; e < e1; e += 1024) atomicAdd(&lcur[dst[e] >> 6], 1);
    __syncthreads();
    int v = lcur[tid];
    part[tid] = v;
    __syncthreads();
    for (int d = 1; d < 1024; d <<= 1) {
        int u = (tid >= d) ? part[tid - d] : 0;
        __syncthreads();
        part[tid] += u;
        __syncthreads();
    }
    int ex = part[tid] - v;
    lbase[tid] = ex;
    if (tid == 1023) lbase[1024] = part[1023];
    lcur[tid] = ex;
    lres[tid] = (v > 0) ? atomicAdd(&bcnt[tid * 16], v) : 0;
    __syncthreads();
    for (int e = e0 + tid; e < e1; e += 1024) {
        int d = dst[e], s = src[e];
        int p = atomicAdd(&lcur[d >> 6], 1);
        lpairs[p] = ((unsigned int)s << 6) | (unsigned int)(d & 63);
    }
    __syncthreads();
    for (int j = tid; j < cnt; j += 1024) {
        int lo = 0, hi = 1023;
        while (lo < hi) { int m = (lo + hi + 1) >> 1; if (lbase[m] <= j) lo = m; else hi = m - 1; }
        int gpos = lres[lo] + (j - lbase[lo]);
        if (gpos < BCAP) bpairs[(size_t)lo * BCAP + gpos] = lpairs[j];
    }
}

// Phase 2: per-bucket LDS histogram -> node degrees.
__global__ __launch_bounds__(256) void deg_kernel(const int* __restrict__ bcnt,
                                                  const unsigned int* __restrict__ bpairs,
                                                  int* __restrict__ off, int n) {
    __shared__ int lh[64];
    int b = blockIdx.x, tid = threadIdx.x;
    if (tid < 64) lh[tid] = 0;
    __syncthreads();
    int cnt = bcnt[b * 16]; if (cnt > BCAP) cnt = BCAP;
    const unsigned int* bp = bpairs + (size_t)b * BCAP;
    for (int i = tid; i < cnt; i += 256) atomicAdd(&lh[bp[i] & 63u], 1);
    __syncthreads();
    if (tid < 64) {
        int node = b * 64 + tid;
        if (node < n) off[node] = lh[tid];
    }
}

// Phase A: blocksums[b] = sum(off[b*1024 .. +1023])
__global__ void block_sum_kernel(const int* __restrict__ off, int* __restrict__ bs, int n) {
    int b = blockIdx.x, t = threadIdx.x;   // 256 threads
    int base = b * 1024;
    int s = 0;
    #pragma unroll
    for (int i = 0; i < 4; ++i) {
        int idx = base + t + 256 * i;
        if (idx < n) s += off[idx];
    }
    #pragma unroll
    for (int d = 32; d; d >>= 1) s += __shfl_down(s, d, 64);
    __shared__ int ws[4];
    if ((t & 63) == 0) ws[t >> 6] = s;
    __syncthreads();
    if (t == 0) bs[b] = ws[0] + ws[1] + ws[2] + ws[3];
}

__global__ void scan_blocksums_kernel(int* __restrict__ bs, int nb,
                                      int* __restrict__ off, int n) {
    __shared__ int l[1024];
    int t = threadIdx.x;
    int v = (t < nb) ? bs[t] : 0;
    l[t] = v;
    __syncthreads();
    for (int d = 1; d < 1024; d <<= 1) {
        int u = (t >= d) ? l[t - d] : 0;
        __syncthreads();
        l[t] += u;
        __syncthreads();
    }
    if (t < nb) bs[t] = (t == 0) ? 0 : l[t - 1];
    if (t == 1023) off[n] = l[1023];
}

__global__ __launch_bounds__(256) void block_scan_kernel(
    int* __restrict__ off, const int* __restrict__ bs, int n) {
    __shared__ int l[1024];
    __shared__ int part[256];
    int b = blockIdx.x, t = threadIdx.x;
    int base = b * 1024;
    #pragma unroll
    for (int i = 0; i < 4; ++i) {
        int idx = base + t + 256 * i;
        l[t + 256 * i] = (idx < n) ? off[idx] : 0;
    }
    __syncthreads();
    int v0 = l[4 * t], v1 = l[4 * t + 1], v2 = l[4 * t + 2], v3 = l[4 * t + 3];
    int p = v0 + v1 + v2 + v3;
    part[t] = p;
    __syncthreads();
    for (int d = 1; d < 256; d <<= 1) {
        int u = (t >= d) ? part[t - d] : 0;
        __syncthreads();
        part[t] += u;
        __syncthreads();
    }
    int ex = bs[b] + ((t == 0) ? 0 : part[t - 1]);
    int e0 = ex, e1 = ex + v0, e2 = e1 + v1, e3 = e2 + v2;
    int idx = base + 4 * t;
    if (idx + 3 < n) {
        ((int4*)(off + idx))[0] = make_int4(e0, e1, e2, e3);
    } else {
        if (idx + 0 < n) off[idx + 0] = e0;
        if (idx + 1 < n) off[idx + 1] = e1;
        if (idx + 2 < n) off[idx + 2] = e2;
    }
}

// Phase 3: per-bucket scatter with LDS cursors.
__global__ __launch_bounds__(256) void bucket_scatter_kernel(
    const int* __restrict__ bcnt, const unsigned int* __restrict__ bpairs,
    const int* __restrict__ off, int* __restrict__ srcs, int n) {
    __shared__ int lcur[64];
    int b = blockIdx.x, tid = threadIdx.x;
    if (tid < 64) {
        int node = b * 64 + tid;
        lcur[tid] = (node < n) ? off[node] : 0;
    }
    __syncthreads();
    int cnt = bcnt[b * 16]; if (cnt > BCAP) cnt = BCAP;
    const unsigned int* bp = bpairs + (size_t)b * BCAP;
    for (int i = tid; i < cnt; i += 256) {
        unsigned int pr = bp[i];
        int pos = atomicAdd(&lcur[pr & 63u], 1);
        srcs[pos] = (int)(pr >> 6);
    }
}

// ---------------- fused setup: xbf(sliced) | gstart | weff | wprep -----------
__global__ __launch_bounds__(256) void setup_kernel(
    const float* __restrict__ x, unsigned int* __restrict__ xbf, long pairs, int nxb,
    const int* __restrict__ batch, int* __restrict__ gstart, int n, int G,
    const float* __restrict__ W2f, const float* __restrict__ b2f,
    const float* __restrict__ fcw, float* __restrict__ weff,
    const float* __restrict__ W0, const float* __restrict__ W1,
    const float* __restrict__ W2, const float* __restrict__ W3,
    const float* __restrict__ W4, unsigned short* __restrict__ Wswz) {
    int b = blockIdx.x, tid = threadIdx.x;
    if (b < nxb) {                       // cast x -> SLICED packed bf16 [4][n][16 dwords]
        long i = (long)b * 256 + tid;    // i = node*64 + dglob (dword index)
        if (i < pairs) {
            float2 v = ((const float2*)x)[i];
            unsigned int pk = (unsigned int)f2bf(v.x) | ((unsigned int)f2bf(v.y) << 16);
            long node = i >> 6;
            int dg = (int)(i & 63);
            int slice = dg >> 4, d = dg & 15;
            xbf[(size_t)slice * n * 16 + node * 16 + d] = pk;
        }
    } else if (b < nxb + 2) {            // gstart[g] = lower_bound(batch, g)
        int i = (b - nxb) * 256 + tid;
        if (i <= G) {
            int lo = 0, hi = n;
            while (lo < hi) { int m = (lo + hi) >> 1; if (batch[m] < i) lo = m + 1; else hi = m; }
            gstart[i] = lo;
        }
    } else if (b == nxb + 2) {           // weff = W2@fcw ; weff[128] = b2.fcw
        int lane = tid & 63, wave = tid >> 6;
        float2 f2 = ((const float2*)fcw)[lane];
        for (int r = wave; r < 128; r += 4) {
            float2 w = ((const float2*)(W2f + r * FEAT))[lane];
            float d = w.x * f2.x + w.y * f2.y;
            #pragma unroll
            for (int s = 32; s; s >>= 1) d += __shfl_down(d, s, 64);
            if (lane == 0) weff[r] = d;
        }
        if (wave == 0) {
            float2 bb = ((const float2*)b2f)[lane];
            float d = bb.x * f2.x + bb.y * f2.y;
            #pragma unroll
            for (int s = 32; s; s >>= 1) d += __shfl_down(d, s, 64);
            if (lane == 0) weff[128] = d;
        }
    } else {                             // wprep: swizzled bf16 weights
        int gid = (b - nxb - 3) * 256 + tid;
        if (gid < 5 * 2048) {
            int mat = gid >> 11;
            int task = gid & 2047;
            int c = task >> 4, m = task & 15;
            const float* W = (mat == 0) ? W0 : (mat == 1) ? W1 : (mat == 2) ? W2 :
                             (mat == 3) ? W3 : W4;
            unsigned short* dp = Wswz + mat * 16384 + c * 128 + ((m ^ (c & 7)) << 3);
            #pragma unroll
            for (int j = 0; j < 8; ++j) dp[j] = f2bf(W[(8 * m + j) * FEAT + c]);
        }
    }
}

// ---------------- aggregation + (1+eps)*h -> sliced bf16 pre -----------------
// Sliced tables [4][n][16 dwords]. Block = 32 nodes x 1 slice; slice = blockIdx&3
// (pins slice s to XCDs {s,s+4}; 3.2MB slice L2-resident). Wave = 8 node-groups
// x 8 lanes; lane loads uint2 (8B) -> group gather = 64B contiguous. 8-deep unroll.
__global__ __launch_bounds__(256) void agg_kernel(
    const unsigned int* __restrict__ hs, const int* __restrict__ off,
    const int* __restrict__ srcs, const float* __restrict__ eps_p,
    unsigned int* __restrict__ pre, int n) {
    int b = blockIdx.x;
    int slice = b & 3;
    int chunk = b >> 2;
    int tid = threadIdx.x;
    int wave = tid >> 6, lane = tid & 63;
    int g = lane >> 3, d = lane & 7;     // lane handles dwords 2d, 2d+1
    int node = chunk * 32 + wave * 8 + g;
    if (node >= n) return;
    float eps1 = 1.0f + eps_p[0];
    const uint2* hb = (const uint2*)(hs + (size_t)slice * n * 16);  // row = 8 uint2
    uint2 su = hb[(size_t)node * 8 + d];
    float2 sa = bfpair(su.x), sb = bfpair(su.y);
    float4 acc0 = make_float4(sa.x * eps1, sa.y * eps1, sb.x * eps1, sb.y * eps1);
    float4 acc1 = make_float4(0.f, 0.f, 0.f, 0.f);
    float4 acc2 = make_float4(0.f, 0.f, 0.f, 0.f);
    float4 acc3 = make_float4(0.f, 0.f, 0.f, 0.f);
    int j0 = off[node], j1 = off[node + 1];
    int j = j0;
    #define ACC(A, U) { float2 p0 = bfpair(U.x), p1 = bfpair(U.y); \
        A.x += p0.x; A.y += p0.y; A.z += p1.x; A.w += p1.y; }
    for (; j + 8 <= j1; j += 8) {
        int s0 = srcs[j], s1 = srcs[j + 1], s2 = srcs[j + 2], s3 = srcs[j + 3];
        int s4 = srcs[j + 4], s5 = srcs[j + 5], s6 = srcs[j + 6], s7 = srcs[j + 7];
        uint2 u0 = hb[(size_t)s0 * 8 + d];
        uint2 u1 = hb[(size_t)s1 * 8 + d];
        uint2 u2 = hb[(size_t)s2 * 8 + d];
        uint2 u3 = hb[(size_t)s3 * 8 + d];
        uint2 u4 = hb[(size_t)s4 * 8 + d];
        uint2 u5 = hb[(size_t)s5 * 8 + d];
        uint2 u6 = hb[(size_t)s6 * 8 + d];
        uint2 u7 = hb[(size_t)s7 * 8 + d];
        ACC(acc0, u0) ACC(acc1, u1) ACC(acc2, u2) ACC(acc3, u3)
        ACC(acc0, u4) ACC(acc1, u5) ACC(acc2, u6) ACC(acc3, u7)
    }
    for (; j + 4 <= j1; j += 4) {
        int s0 = srcs[j], s1 = srcs[j + 1], s2 = srcs[j + 2], s3 = srcs[j + 3];
        uint2 u0 = hb[(size_t)s0 * 8 + d];
        uint2 u1 = hb[(size_t)s1 * 8 + d];
        uint2 u2 = hb[(size_t)s2 * 8 + d];
        uint2 u3 = hb[(size_t)s3 * 8 + d];
        ACC(acc0, u0) ACC(acc1, u1) ACC(acc2, u2) ACC(acc3, u3)
    }
    for (; j < j1; ++j) {
        uint2 u = hb[(size_t)srcs[j] * 8 + d];
        ACC(acc0, u)
    }
    #undef ACC
    acc0.x += acc1.x + acc2.x;  acc0.y += acc1.y + acc2.y;
    acc0.z += acc1.z + acc2.z;  acc0.w += acc1.w + acc2.w;
    acc0.x += acc3.x;  acc0.y += acc3.y;
    acc0.z += acc3.z;  acc0.w += acc3.w;
    uint2 o;
    o.x = (unsigned int)f2bf(acc0.x) | ((unsigned int)f2bf(acc0.y) << 16);
    o.y = (unsigned int)f2bf(acc0.z) | ((unsigned int)f2bf(acc0.w) << 16);
    ((uint2*)(pre + (size_t)slice * n * 16))[(size_t)node * 8 + d] = o;
}

// ---------------- bf16 MFMA GEMM over SLICED A. MODE 1: sliced store. MODE 2: pool ----
// A sliced [4][n][32] bf16: feats 32k0+8q..+7 live at slice k0, elem 8q.
template <int MODE>
__global__ __launch_bounds__(256) void mfma_mlp_kernel(
    const unsigned short* __restrict__ A, const unsigned short* __restrict__ Wswz,
    const float* __restrict__ bias, unsigned short* __restrict__ outbf,
    const int* __restrict__ batch, const float* __restrict__ weff,
    float* __restrict__ sums, int n) {
    __shared__ int4 Wl4[2048];   // 32KB swizzled W
    int tid = threadIdx.x;
    const int4* ws4 = (const int4*)Wswz;
    #pragma unroll
    for (int i = 0; i < 8; ++i) Wl4[i * 256 + tid] = ws4[i * 256 + tid];
    __syncthreads();
    const unsigned short* Wl = (const unsigned short*)Wl4;

    int lane = tid & 63, wave = tid >> 6;
    int q = lane >> 4, c15 = lane & 15;
    int r0 = blockIdx.x * 64 + wave * 16;
    int arow = r0 + c15;
    bool rv = arow < n;
    size_t sstride = (size_t)n * 32;     // shorts per slice
    const unsigned short* abase = A + (size_t)arow * 32 + 8 * q;

    f32x4 zf = {0.f, 0.f, 0.f, 0.f};
    f32x4 acc[8];
    #pragma unroll
    for (int i = 0; i < 8; ++i) acc[i] = zf;
    bf16x8 zero8 = {0, 0, 0, 0, 0, 0, 0, 0};

    #pragma unroll
    for (int k0 = 0; k0 < 4; ++k0) {
        bf16x8 a = rv ? *(const bf16x8*)(abase + (size_t)k0 * sstride) : zero8;
        int m = k0 * 4 + q;
        #pragma unroll
        for (int nt = 0; nt < 8; ++nt) {
            int col = nt * 16 + c15;
            bf16x8 bfr = *(const bf16x8*)&Wl[col * 128 + ((m ^ (col & 7)) << 3)];
            acc[nt] = __builtin_amdgcn_mfma_f32_16x16x32_bf16(a, bfr, acc[nt], 0, 0, 0);
        }
    }

    int orow0 = r0 + q * 4;
    if (MODE == 1) {
        #pragma unroll
        for (int nt = 0; nt < 8; ++nt) {
            float bv = bias[nt * 16 + c15];
            size_t sb = (size_t)(nt >> 1) * sstride + (nt & 1) * 16 + c15;
            #pragma unroll
            for (int r = 0; r < 4; ++r) {
                int ro = orow0 + r;
                if (ro < n) {
                    float v = fmaxf(acc[nt][r] + bv, 0.f);
                    outbf[sb + (size_t)ro * 32] = f2bf(v);
                }
            }
        }
    } else {
        // fused pool: rowdot = relu(row)·weff ; per-graph LDS accumulation.
        __shared__ float gsum[64];
        int r0b = blockIdx.x * 64;
        int lastn = r0b + 63 < n - 1 ? r0b + 63 : n - 1;
        int gmin = batch[r0b];
        int gmax = batch[lastn];
        int span = gmax - gmin + 1;
        bool lds_ok = (span <= 64);
        if (lds_ok) for (int i = tid; i < span; i += 256) gsum[i] = 0.f;
        __syncthreads();
        float rowdot[4] = {0.f, 0.f, 0.f, 0.f};
        #pragma unroll
        for (int nt = 0; nt < 8; ++nt) {
            int col = nt * 16 + c15;
            float bv = bias[col];
            float wv = weff[col];
            #pragma unroll
            for (int r = 0; r < 4; ++r)
                rowdot[r] += fmaxf(acc[nt][r] + bv, 0.f) * wv;
        }
        #pragma unroll
        for (int r = 0; r < 4; ++r) {
            float v = rowdot[r];
            v += __shfl_xor(v, 1, 64);
            v += __shfl_xor(v, 2, 64);
            v += __shfl_xor(v, 4, 64);
            v += __shfl_xor(v, 8, 64);
            if (c15 == 0) {
                int node = orow0 + r;
                if (node < n) {
                    int g = batch[node];
                    if (lds_ok) atomicAdd(&gsum[g - gmin], v);
                    else        atomicAdd(&sums[g], v);
                }
            }
        }
        __syncthreads();
        if (lds_ok)
            for (int i = tid; i < span; i += 256) atomicAdd(&sums[gmin + i], gsum[i]);
    }
}

// ---------------- finalize: out[g] = sums/cnt + b2.fcw + fcb ----------------
__global__ void finalize_kernel(const float* __restrict__ sums, const int* __restrict__ gstart,
                                const float* __restrict__ weff, const float* __restrict__ fcb,
                                float* __restrict__ out, int G) {
    int g = blockIdx.x * blockDim.x + threadIdx.x;
    if (g >= G) return;
    int cnt = gstart[g + 1] - gstart[g];
    out[g] = (cnt > 0) ? sums[g] / (float)cnt + weff[128] + fcb[0] : fcb[0];
}

static inline size_t align256(size_t x) { return (x + 255) & ~(size_t)255; }

extern "C" void kernel_launch(void* const* d_in, const int* in_sizes, int n_in,
                              void* d_out, int out_size, void* d_ws, size_t ws_size,
                              hipStream_t stream) {
    const float* x      = (const float*)d_in[0];
    const int*   ei     = (const int*)d_in[1];
    const int*   batch  = (const int*)d_in[2];
    const float* W1[3]  = {(const float*)d_in[3],  (const float*)d_in[8],  (const float*)d_in[13]};
    const float* b1[3]  = {(const float*)d_in[4],  (const float*)d_in[9],  (const float*)d_in[14]};
    const float* W2[3]  = {(const float*)d_in[5],  (const float*)d_in[10], (const float*)d_in[15]};
    const float* b2[3]  = {(const float*)d_in[6],  (const float*)d_in[11], (const float*)d_in[16]};
    const float* eps[3] = {(const float*)d_in[7],  (const float*)d_in[12], (const float*)d_in[17]};
    const float* fcw    = (const float*)d_in[18];
    const float* fcb    = (const float*)d_in[19];
    float* out = (float*)d_out;

    const int N = in_sizes[0] / FEAT;
    const int E = in_sizes[1] / 2;
    const int G = out_size;
    const int nbuckets = (N + 63) >> 6;

    // workspace layout
    char* p = (char*)d_ws;
    int* off    = (int*)p;  p += align256((size_t)(N + 1) * 4);
    int* srcs   = (int*)p;  p += align256((size_t)E * 4);
    int* bsums  = (int*)p;  p += align256((size_t)1024 * 4);
    int* gstart = (int*)p;  p += align256((size_t)(G + 1) * 4);
    float* weff = (float*)p; p += align256((size_t)256 * 4);
    unsigned short* Wswz = (unsigned short*)p; p += align256((size_t)5 * 16384 * 2);
    float* sums = (float*)p;                     // zero-init region start
    char* z0 = (char*)sums;
    p += align256((size_t)G * 4);
    int* bcnt = (int*)p; p += align256((size_t)nbuckets * 16 * 4);
    size_t zbytes = (size_t)(p - z0);            // sums + bcnt in one memset
    unsigned int* bpairs = (unsigned int*)p;     p += align256((size_t)nbuckets * BCAP * 4);
    unsigned int* x_bf   = (unsigned int*)p;     p += align256((size_t)N * 64 * 4);
    unsigned int* pre_bf = (unsigned int*)p;     p += align256((size_t)N * 64 * 4);
    unsigned int* t_bf   = (unsigned int*)p;     p += align256((size_t)N * 64 * 4);
    unsigned int* h_bf   = (unsigned int*)p;     p += align256((size_t)N * 64 * 4);
    (void)ws_size; (void)n_in;

    const int* src = ei;        // edge_index[0]
    const int* dst = ei + E;    // edge_index[1]

    hipMemsetAsync(z0, 0, zbytes, stream);

    // CSR build: LDS-binned bucket (1024 thr) -> deg -> scan -> bucket_scatter
    const int nb = (N + 1023) / 1024;
    const int nchunks = (E + CHUNK - 1) / CHUNK;
    bucket_kernel<<<nchunks, 1024, 0, stream>>>(src, dst, bcnt, bpairs, E);
    deg_kernel<<<nbuckets, 256, 0, stream>>>(bcnt, bpairs, off, N);
    block_sum_kernel<<<nb, 256, 0, stream>>>(off, bsums, N);
    scan_blocksums_kernel<<<1, 1024, 0, stream>>>(bsums, nb, off, N);
    block_scan_kernel<<<nb, 256, 0, stream>>>(off, bsums, N);
    bucket_scatter_kernel<<<nbuckets, 256, 0, stream>>>(bcnt, bpairs, off, srcs, N);

    // fused setup (independent of CSR): xbf(sliced) | gstart | weff | wprep
    long pairs = (long)N * 64;
    int nxb = (int)((pairs + 255) / 256);
    setup_kernel<<<nxb + 43, 256, 0, stream>>>(
        x, x_bf, pairs, nxb, batch, gstart, N, G,
        W2[2], b2[2], fcw, weff,
        W1[0], W2[0], W1[1], W2[1], W1[2], Wswz);

    const int aggBlocks  = 4 * ((N + 31) / 32);   // 4 slices, 32 nodes/block
    const int gemmBlocks = (N + 63) / 64;
    const unsigned short* Wz[5] = {Wswz, Wswz + 16384, Wswz + 2 * 16384,
                                   Wswz + 3 * 16384, Wswz + 4 * 16384};

    // layers 0,1: agg -> gemm1(sliced bf16) -> gemm2(sliced bf16)
    const unsigned int* h = x_bf;
    for (int i = 0; i < 2; ++i) {
        agg_kernel<<<aggBlocks, 256, 0, stream>>>(h, off, srcs, eps[i], pre_bf, N);
        mfma_mlp_kernel<1><<<gemmBlocks, 256, 0, stream>>>(
            (const unsigned short*)pre_bf, Wz[2 * i], b1[i], (unsigned short*)t_bf,
            nullptr, nullptr, nullptr, N);
        mfma_mlp_kernel<1><<<gemmBlocks, 256, 0, stream>>>(
            (const unsigned short*)t_bf, Wz[2 * i + 1], b2[i], (unsigned short*)h_bf,
            nullptr, nullptr, nullptr, N);
        h = h_bf;
    }
    // layer 2: agg -> gemm1 with fused pooled-dot epilogue (W2_2+fc folded via weff)
    agg_kernel<<<aggBlocks, 256, 0, stream>>>(h, off, srcs, eps[2], pre_bf, N);
    mfma_mlp_kernel<2><<<gemmBlocks, 256, 0, stream>>>(
        (const unsigned short*)pre_bf, Wz[4], b1[2], nullptr,
        batch, weff, sums, N);

    finalize_kernel<<<(G + 255) / 256, 256, 0, stream>>>(sums, gstart, weff, fcb, out, G);
}

// Round 12
// 295.538 us; speedup vs baseline: 1.1362x; 1.0310x over previous
//
#include <hip/hip_runtime.h>

// GIN regressor: 3x [segment-sum aggregation -> (1+eps)*x+agg -> Linear/ReLU/Linear]
// -> global mean pool -> fc.
// CSR: LDS-binned coarse-bucket counting sort -> tiny bucket-count scan (782
// values; per-bucket count == degree-sum of its 64 nodes) -> ONE fused kernel
// (histogram + 64-wide wave scan + off write + LDS-cursor scatter). 3 dispatches.
// Feature tables FEATURE-SLICED [4][N][32] bf16 (3.2MB/slice, L2-resident;
// blockIdx&3 pins slices across XCDs). Agg gathers uint4/lane (4-lane groups,
// 16 nodes/wave, 8-deep unroll) - r11 lesson: latency/issue-bound, so fewer,
// wider loads win. GEMMs = bf16 MFMA, pre-swizzled W, sliced A.
// Layer-2: second GEMM folded into pool (weff = W2@fcw); its first GEMM's
// epilogue computes pooled per-graph sums directly.

#define FEAT 128
#define BCAP 2048          // per-bucket capacity (mean load ~1024)
#define CHUNK 10240        // edges per bucket-kernel block

typedef short  bf16x8 __attribute__((ext_vector_type(8)));
typedef float  f32x4  __attribute__((ext_vector_type(4)));

__device__ inline unsigned short f2bf(float f) {  // round-to-nearest-even fp32->bf16
    unsigned int u = __float_as_uint(f);
    u = (u + 0x7FFFu + ((u >> 16) & 1u)) >> 16;
    return (unsigned short)u;
}
__device__ inline float2 bfpair(unsigned int u) { // packed 2x bf16 -> 2x fp32
    float2 r;
    r.x = __uint_as_float(u << 16);
    r.y = __uint_as_float(u & 0xffff0000u);
    return r;
}

// ---------------- CSR build: LDS-binned coarse-bucket counting sort ----------
__global__ __launch_bounds__(1024) void bucket_kernel(
    const int* __restrict__ src, const int* __restrict__ dst,
    int* __restrict__ bcnt, unsigned int* __restrict__ bpairs, int E) {
    __shared__ unsigned int lpairs[CHUNK];   // 40KB: bucket-ordered pairs
    __shared__ int lbase[1025];
    __shared__ int lcur[1024];
    __shared__ int lres[1024];
    __shared__ int part[1024];
    int tid = threadIdx.x;
    int e0 = blockIdx.x * CHUNK;
    int e1 = e0 + CHUNK; if (e1 > E) e1 = E;
    int cnt = e1 - e0;
    lcur[tid] = 0;
    __syncthreads();
    for (int e = e0 + tid; e < e1; e += 1024) atomicAdd(&lcur[dst[e] >> 6], 1);
    __syncthreads();
    int v = lcur[tid];
    part[tid] = v;
    __syncthreads();
    for (int d = 1; d < 1024; d <<= 1) {
        int u = (tid >= d) ? part[tid - d] : 0;
        __syncthreads();
        part[tid] += u;
        __syncthreads();
    }
    int ex = part[tid] - v;
    lbase[tid] = ex;
    if (tid == 1023) lbase[1024] = part[1023];
    lcur[tid] = ex;
    lres[tid] = (v > 0) ? atomicAdd(&bcnt[tid * 16], v) : 0;
    __syncthreads();
    for (int e = e0 + tid; e < e1; e += 1024) {
        int d = dst[e], s = src[e];
        int p = atomicAdd(&lcur[d >> 6], 1);
        lpairs[p] = ((unsigned int)s << 6) | (unsigned int)(d & 63);
    }
    __syncthreads();
    for (int j = tid; j < cnt; j += 1024) {
        int lo = 0, hi = 1023;
        while (lo < hi) { int m = (lo + hi + 1) >> 1; if (lbase[m] <= j) lo = m; else hi = m - 1; }
        int gpos = lres[lo] + (j - lbase[lo]);
        if (gpos < BCAP) bpairs[(size_t)lo * BCAP + gpos] = lpairs[j];
    }
}

// scan of per-bucket counts (nbuckets <= 1024): bbase[b] = exclusive sum; off[n]=E.
__global__ void scan_bcnt_kernel(const int* __restrict__ bcnt, int* __restrict__ bbase,
                                 int* __restrict__ off, int n, int nbuckets) {
    __shared__ int l[1024];
    int t = threadIdx.x;
    int v = (t < nbuckets) ? bcnt[t * 16] : 0;
    l[t] = v;
    __syncthreads();
    for (int d = 1; d < 1024; d <<= 1) {
        int u = (t >= d) ? l[t - d] : 0;
        __syncthreads();
        l[t] += u;
        __syncthreads();
    }
    if (t < nbuckets) bbase[t] = l[t] - v;
    if (t == 1023) off[n] = l[1023];
}

// FUSED per-bucket: histogram -> 64-wide wave scan -> off write -> cursor scatter.
__global__ __launch_bounds__(256) void degscat_kernel(
    const int* __restrict__ bcnt, const int* __restrict__ bbase,
    const unsigned int* __restrict__ bpairs,
    int* __restrict__ off, int* __restrict__ srcs, int n) {
    __shared__ int lh[64];
    __shared__ int lcur[64];
    int b = blockIdx.x, tid = threadIdx.x;
    if (tid < 64) lh[tid] = 0;
    __syncthreads();
    int cnt = bcnt[b * 16]; if (cnt > BCAP) cnt = BCAP;
    int base = bbase[b];
    const unsigned int* bp = bpairs + (size_t)b * BCAP;
    for (int i = tid; i < cnt; i += 256) atomicAdd(&lh[bp[i] & 63u], 1);
    __syncthreads();
    if (tid < 64) {                       // wave 0: exclusive scan over 64 degrees
        int v = lh[tid];
        int inc = v;
        #pragma unroll
        for (int d = 1; d < 64; d <<= 1) {
            int u = __shfl_up(inc, d, 64);
            if (tid >= d) inc += u;
        }
        int ex = base + inc - v;
        int node = b * 64 + tid;
        if (node < n) off[node] = ex;
        lcur[tid] = ex;
    }
    __syncthreads();
    for (int i = tid; i < cnt; i += 256) {
        unsigned int pr = bp[i];
        int pos = atomicAdd(&lcur[pr & 63u], 1);
        srcs[pos] = (int)(pr >> 6);
    }
}

// ---------------- fused setup: xbf(sliced) | gstart | weff | wprep -----------
__global__ __launch_bounds__(256) void setup_kernel(
    const float* __restrict__ x, unsigned int* __restrict__ xbf, long pairs, int nxb,
    const int* __restrict__ batch, int* __restrict__ gstart, int n, int G,
    const float* __restrict__ W2f, const float* __restrict__ b2f,
    const float* __restrict__ fcw, float* __restrict__ weff,
    const float* __restrict__ W0, const float* __restrict__ W1,
    const float* __restrict__ W2, const float* __restrict__ W3,
    const float* __restrict__ W4, unsigned short* __restrict__ Wswz) {
    int b = blockIdx.x, tid = threadIdx.x;
    if (b < nxb) {                       // cast x -> SLICED packed bf16 [4][n][16 dwords]
        long i = (long)b * 256 + tid;    // i = node*64 + dglob (dword index)
        if (i < pairs) {
            float2 v = ((const float2*)x)[i];
            unsigned int pk = (unsigned int)f2bf(v.x) | ((unsigned int)f2bf(v.y) << 16);
            long node = i >> 6;
            int dg = (int)(i & 63);
            int slice = dg >> 4, d = dg & 15;
            xbf[(size_t)slice * n * 16 + node * 16 + d] = pk;
        }
    } else if (b < nxb + 2) {            // gstart[g] = lower_bound(batch, g)
        int i = (b - nxb) * 256 + tid;
        if (i <= G) {
            int lo = 0, hi = n;
            while (lo < hi) { int m = (lo + hi) >> 1; if (batch[m] < i) lo = m + 1; else hi = m; }
            gstart[i] = lo;
        }
    } else if (b == nxb + 2) {           // weff = W2@fcw ; weff[128] = b2.fcw
        int lane = tid & 63, wave = tid >> 6;
        float2 f2 = ((const float2*)fcw)[lane];
        for (int r = wave; r < 128; r += 4) {
            float2 w = ((const float2*)(W2f + r * FEAT))[lane];
            float d = w.x * f2.x + w.y * f2.y;
            #pragma unroll
            for (int s = 32; s; s >>= 1) d += __shfl_down(d, s, 64);
            if (lane == 0) weff[r] = d;
        }
        if (wave == 0) {
            float2 bb = ((const float2*)b2f)[lane];
            float d = bb.x * f2.x + bb.y * f2.y;
            #pragma unroll
            for (int s = 32; s; s >>= 1) d += __shfl_down(d, s, 64);
            if (lane == 0) weff[128] = d;
        }
    } else {                             // wprep: swizzled bf16 weights
        int gid = (b - nxb - 3) * 256 + tid;
        if (gid < 5 * 2048) {
            int mat = gid >> 11;
            int task = gid & 2047;
            int c = task >> 4, m = task & 15;
            const float* W = (mat == 0) ? W0 : (mat == 1) ? W1 : (mat == 2) ? W2 :
                             (mat == 3) ? W3 : W4;
            unsigned short* dp = Wswz + mat * 16384 + c * 128 + ((m ^ (c & 7)) << 3);
            #pragma unroll
            for (int j = 0; j < 8; ++j) dp[j] = f2bf(W[(8 * m + j) * FEAT + c]);
        }
    }
}

// ---------------- aggregation + (1+eps)*h -> sliced bf16 pre -----------------
// Sliced tables [4][n][16 dwords]. Block = 64 nodes x 1 slice (slice=blockIdx&3).
// Lane group = 4 lanes x uint4 (16B) -> node row gather = 64B contiguous;
// 16 nodes/wave; 8-deep unroll (128B in flight per lane).
__global__ __launch_bounds__(256) void agg_kernel(
    const unsigned int* __restrict__ hs, const int* __restrict__ off,
    const int* __restrict__ srcs, const float* __restrict__ eps_p,
    unsigned int* __restrict__ pre, int n) {
    int b = blockIdx.x;
    int slice = b & 3;
    int chunk = b >> 2;
    int tid = threadIdx.x;
    int wave = tid >> 6, lane = tid & 63;
    int g = lane >> 2, d = lane & 3;     // lane handles dwords 4d..4d+3 (feats 8d..8d+7)
    int node = chunk * 64 + wave * 16 + g;
    if (node >= n) return;
    float eps1 = 1.0f + eps_p[0];
    const uint4* hb = (const uint4*)(hs + (size_t)slice * n * 16);  // row = 4 uint4
    uint4 su = hb[(size_t)node * 4 + d];
    float2 p0 = bfpair(su.x), p1 = bfpair(su.y), p2 = bfpair(su.z), p3 = bfpair(su.w);
    float4 a0 = make_float4(p0.x * eps1, p0.y * eps1, p1.x * eps1, p1.y * eps1);
    float4 b0 = make_float4(p2.x * eps1, p2.y * eps1, p3.x * eps1, p3.y * eps1);
    float4 a1 = make_float4(0.f, 0.f, 0.f, 0.f), b1v = a1;
    float4 a2 = a1, b2v = a1;
    float4 a3 = a1, b3v = a1;
    int j0 = off[node], j1 = off[node + 1];
    int j = j0;
    #define ACC(A, B, U) { float2 q0 = bfpair(U.x), q1 = bfpair(U.y), \
                                  q2 = bfpair(U.z), q3 = bfpair(U.w); \
        A.x += q0.x; A.y += q0.y; A.z += q1.x; A.w += q1.y; \
        B.x += q2.x; B.y += q2.y; B.z += q3.x; B.w += q3.y; }
    for (; j + 8 <= j1; j += 8) {
        int s0 = srcs[j], s1 = srcs[j + 1], s2 = srcs[j + 2], s3 = srcs[j + 3];
        int s4 = srcs[j + 4], s5 = srcs[j + 5], s6 = srcs[j + 6], s7 = srcs[j + 7];
        uint4 u0 = hb[(size_t)s0 * 4 + d];
        uint4 u1 = hb[(size_t)s1 * 4 + d];
        uint4 u2 = hb[(size_t)s2 * 4 + d];
        uint4 u3 = hb[(size_t)s3 * 4 + d];
        uint4 u4 = hb[(size_t)s4 * 4 + d];
        uint4 u5 = hb[(size_t)s5 * 4 + d];
        uint4 u6 = hb[(size_t)s6 * 4 + d];
        uint4 u7 = hb[(size_t)s7 * 4 + d];
        ACC(a0, b0, u0) ACC(a1, b1v, u1) ACC(a2, b2v, u2) ACC(a3, b3v, u3)
        ACC(a0, b0, u4) ACC(a1, b1v, u5) ACC(a2, b2v, u6) ACC(a3, b3v, u7)
    }
    for (; j + 4 <= j1; j += 4) {
        int s0 = srcs[j], s1 = srcs[j + 1], s2 = srcs[j + 2], s3 = srcs[j + 3];
        uint4 u0 = hb[(size_t)s0 * 4 + d];
        uint4 u1 = hb[(size_t)s1 * 4 + d];
        uint4 u2 = hb[(size_t)s2 * 4 + d];
        uint4 u3 = hb[(size_t)s3 * 4 + d];
        ACC(a0, b0, u0) ACC(a1, b1v, u1) ACC(a2, b2v, u2) ACC(a3, b3v, u3)
    }
    for (; j < j1; ++j) {
        uint4 u = hb[(size_t)srcs[j] * 4 + d];
        ACC(a0, b0, u)
    }
    #undef ACC
    a0.x += a1.x + a2.x;  a0.y += a1.y + a2.y;
    a0.z += a1.z + a2.z;  a0.w += a1.w + a2.w;
    a0.x += a3.x;  a0.y += a3.y;  a0.z += a3.z;  a0.w += a3.w;
    b0.x += b1v.x + b2v.x;  b0.y += b1v.y + b2v.y;
    b0.z += b1v.z + b2v.z;  b0.w += b1v.w + b2v.w;
    b0.x += b3v.x;  b0.y += b3v.y;  b0.z += b3v.z;  b0.w += b3v.w;
    uint4 o;
    o.x = (unsigned int)f2bf(a0.x) | ((unsigned int)f2bf(a0.y) << 16);
    o.y = (unsigned int)f2bf(a0.z) | ((unsigned int)f2bf(a0.w) << 16);
    o.z = (unsigned int)f2bf(b0.x) | ((unsigned int)f2bf(b0.y) << 16);
    o.w = (unsigned int)f2bf(b0.z) | ((unsigned int)f2bf(b0.w) << 16);
    ((uint4*)(pre + (size_t)slice * n * 16))[(size_t)node * 4 + d] = o;
}

// ---------------- bf16 MFMA GEMM over SLICED A. MODE 1: sliced store. MODE 2: pool ----
// A sliced [4][n][32] bf16: feats 32k0+8q..+7 live at slice k0, elem 8q.
template <int MODE>
__global__ __launch_bounds__(256) void mfma_mlp_kernel(
    const unsigned short* __restrict__ A, const unsigned short* __restrict__ Wswz,
    const float* __restrict__ bias, unsigned short* __restrict__ outbf,
    const int* __restrict__ batch, const float* __restrict__ weff,
    float* __restrict__ sums, int n) {
    __shared__ int4 Wl4[2048];   // 32KB swizzled W
    int tid = threadIdx.x;
    const int4* ws4 = (const int4*)Wswz;
    #pragma unroll
    for (int i = 0; i < 8; ++i) Wl4[i * 256 + tid] = ws4[i * 256 + tid];
    __syncthreads();
    const unsigned short* Wl = (const unsigned short*)Wl4;

    int lane = tid & 63, wave = tid >> 6;
    int q = lane >> 4, c15 = lane & 15;
    int r0 = blockIdx.x * 64 + wave * 16;
    int arow = r0 + c15;
    bool rv = arow < n;
    size_t sstride = (size_t)n * 32;     // shorts per slice
    const unsigned short* abase = A + (size_t)arow * 32 + 8 * q;

    f32x4 zf = {0.f, 0.f, 0.f, 0.f};
    f32x4 acc[8];
    #pragma unroll
    for (int i = 0; i < 8; ++i) acc[i] = zf;
    bf16x8 zero8 = {0, 0, 0, 0, 0, 0, 0, 0};

    #pragma unroll
    for (int k0 = 0; k0 < 4; ++k0) {
        bf16x8 a = rv ? *(const bf16x8*)(abase + (size_t)k0 * sstride) : zero8;
        int m = k0 * 4 + q;
        #pragma unroll
        for (int nt = 0; nt < 8; ++nt) {
            int col = nt * 16 + c15;
            bf16x8 bfr = *(const bf16x8*)&Wl[col * 128 + ((m ^ (col & 7)) << 3)];
            acc[nt] = __builtin_amdgcn_mfma_f32_16x16x32_bf16(a, bfr, acc[nt], 0, 0, 0);
        }
    }

    int orow0 = r0 + q * 4;
    if (MODE == 1) {
        #pragma unroll
        for (int nt = 0; nt < 8; ++nt) {
            float bv = bias[nt * 16 + c15];
            size_t sb = (size_t)(nt >> 1) * sstride + (nt & 1) * 16 + c15;
            #pragma unroll
            for (int r = 0; r < 4; ++r) {
                int ro = orow0 + r;
                if (ro < n) {
                    float v = fmaxf(acc[nt][r] + bv, 0.f);
                    outbf[sb + (size_t)ro * 32] = f2bf(v);
                }
            }
        }
    } else {
        // fused pool: rowdot = relu(row)·weff ; per-graph LDS accumulation.
        __shared__ float gsum[64];
        int r0b = blockIdx.x * 64;
        int lastn = r0b + 63 < n - 1 ? r0b + 63 : n - 1;
        int gmin = batch[r0b];
        int gmax = batch[lastn];
        int span = gmax - gmin + 1;
        bool lds_ok = (span <= 64);
        if (lds_ok) for (int i = tid; i < span; i += 256) gsum[i] = 0.f;
        __syncthreads();
        float rowdot[4] = {0.f, 0.f, 0.f, 0.f};
        #pragma unroll
        for (int nt = 0; nt < 8; ++nt) {
            int col = nt * 16 + c15;
            float bv = bias[col];
            float wv = weff[col];
            #pragma unroll
            for (int r = 0; r < 4; ++r)
                rowdot[r] += fmaxf(acc[nt][r] + bv, 0.f) * wv;
        }
        #pragma unroll
        for (int r = 0; r < 4; ++r) {
            float v = rowdot[r];
            v += __shfl_xor(v, 1, 64);
            v += __shfl_xor(v, 2, 64);
            v += __shfl_xor(v, 4, 64);
            v += __shfl_xor(v, 8, 64);
            if (c15 == 0) {
                int node = orow0 + r;
                if (node < n) {
                    int g = batch[node];
                    if (lds_ok) atomicAdd(&gsum[g - gmin], v);
                    else        atomicAdd(&sums[g], v);
                }
            }
        }
        __syncthreads();
        if (lds_ok)
            for (int i = tid; i < span; i += 256) atomicAdd(&sums[gmin + i], gsum[i]);
    }
}

// ---------------- finalize: out[g] = sums/cnt + b2.fcw + fcb ----------------
__global__ void finalize_kernel(const float* __restrict__ sums, const int* __restrict__ gstart,
                                const float* __restrict__ weff, const float* __restrict__ fcb,
                                float* __restrict__ out, int G) {
    int g = blockIdx.x * blockDim.x + threadIdx.x;
    if (g >= G) return;
    int cnt = gstart[g + 1] - gstart[g];
    out[g] = (cnt > 0) ? sums[g] / (float)cnt + weff[128] + fcb[0] : fcb[0];
}

static inline size_t align256(size_t x) { return (x + 255) & ~(size_t)255; }

extern "C" void kernel_launch(void* const* d_in, const int* in_sizes, int n_in,
                              void* d_out, int out_size, void* d_ws, size_t ws_size,
                              hipStream_t stream) {
    const float* x      = (const float*)d_in[0];
    const int*   ei     = (const int*)d_in[1];
    const int*   batch  = (const int*)d_in[2];
    const float* W1[3]  = {(const float*)d_in[3],  (const float*)d_in[8],  (const float*)d_in[13]};
    const float* b1[3]  = {(const float*)d_in[4],  (const float*)d_in[9],  (const float*)d_in[14]};
    const float* W2[3]  = {(const float*)d_in[5],  (const float*)d_in[10], (const float*)d_in[15]};
    const float* b2[3]  = {(const float*)d_in[6],  (const float*)d_in[11], (const float*)d_in[16]};
    const float* eps[3] = {(const float*)d_in[7],  (const float*)d_in[12], (const float*)d_in[17]};
    const float* fcw    = (const float*)d_in[18];
    const float* fcb    = (const float*)d_in[19];
    float* out = (float*)d_out;

    const int N = in_sizes[0] / FEAT;
    const int E = in_sizes[1] / 2;
    const int G = out_size;
    const int nbuckets = (N + 63) >> 6;

    // workspace layout
    char* p = (char*)d_ws;
    int* off    = (int*)p;  p += align256((size_t)(N + 1) * 4);
    int* srcs   = (int*)p;  p += align256((size_t)E * 4);
    int* bbase  = (int*)p;  p += align256((size_t)1024 * 4);
    int* gstart = (int*)p;  p += align256((size_t)(G + 1) * 4);
    float* weff = (float*)p; p += align256((size_t)256 * 4);
    unsigned short* Wswz = (unsigned short*)p; p += align256((size_t)5 * 16384 * 2);
    float* sums = (float*)p;                     // zero-init region start
    char* z0 = (char*)sums;
    p += align256((size_t)G * 4);
    int* bcnt = (int*)p; p += align256((size_t)nbuckets * 16 * 4);
    size_t zbytes = (size_t)(p - z0);            // sums + bcnt in one memset
    unsigned int* bpairs = (unsigned int*)p;     p += align256((size_t)nbuckets * BCAP * 4);
    unsigned int* x_bf   = (unsigned int*)p;     p += align256((size_t)N * 64 * 4);
    unsigned int* pre_bf = (unsigned int*)p;     p += align256((size_t)N * 64 * 4);
    unsigned int* t_bf   = (unsigned int*)p;     p += align256((size_t)N * 64 * 4);
    unsigned int* h_bf   = (unsigned int*)p;     p += align256((size_t)N * 64 * 4);
    (void)ws_size; (void)n_in;

    const int* src = ei;        // edge_index[0]
    const int* dst = ei + E;    // edge_index[1]

    hipMemsetAsync(z0, 0, zbytes, stream);

    // CSR build: bucket (1024 thr) -> scan_bcnt (tiny) -> fused degscat
    const int nchunks = (E + CHUNK - 1) / CHUNK;
    bucket_kernel<<<nchunks, 1024, 0, stream>>>(src, dst, bcnt, bpairs, E);
    scan_bcnt_kernel<<<1, 1024, 0, stream>>>(bcnt, bbase, off, N, nbuckets);
    degscat_kernel<<<nbuckets, 256, 0, stream>>>(bcnt, bbase, bpairs, off, srcs, N);

    // fused setup (independent of CSR): xbf(sliced) | gstart | weff | wprep
    long pairs = (long)N * 64;
    int nxb = (int)((pairs + 255) / 256);
    setup_kernel<<<nxb + 43, 256, 0, stream>>>(
        x, x_bf, pairs, nxb, batch, gstart, N, G,
        W2[2], b2[2], fcw, weff,
        W1[0], W2[0], W1[1], W2[1], W1[2], Wswz);

    const int aggBlocks  = 4 * ((N + 63) / 64);   // 4 slices, 64 nodes/block
    const int gemmBlocks = (N + 63) / 64;
    const unsigned short* Wz[5] = {Wswz, Wswz + 16384, Wswz + 2 * 16384,
                                   Wswz + 3 * 16384, Wswz + 4 * 16384};

    // layers 0,1: agg -> gemm1(sliced bf16) -> gemm2(sliced bf16)
    const unsigned int* h = x_bf;
    for (int i = 0; i < 2; ++i) {
        agg_kernel<<<aggBlocks, 256, 0, stream>>>(h, off, srcs, eps[i], pre_bf, N);
        mfma_mlp_kernel<1><<<gemmBlocks, 256, 0, stream>>>(
            (const unsigned short*)pre_bf, Wz[2 * i], b1[i], (unsigned short*)t_bf,
            nullptr, nullptr, nullptr, N);
        mfma_mlp_kernel<1><<<gemmBlocks, 256, 0, stream>>>(
            (const unsigned short*)t_bf, Wz[2 * i + 1], b2[i], (unsigned short*)h_bf,
            nullptr, nullptr, nullptr, N);
        h = h_bf;
    }
    // layer 2: agg -> gemm1 with fused pooled-dot epilogue (W2_2+fc folded via weff)
    agg_kernel<<<aggBlocks, 256, 0, stream>>>(h, off, srcs, eps[2], pre_bf, N);
    mfma_mlp_kernel<2><<<gemmBlocks, 256, 0, stream>>>(
        (const unsigned short*)pre_bf, Wz[4], b1[2], nullptr,
        batch, weff, sums, N);

    finalize_kernel<<<(G + 255) / 256, 256, 0, stream>>>(sums, gstart, weff, fcb, out, G);
}